// Round 14
// baseline (423.942 us; speedup 1.0000x reference)
//
#include <hip/hip_runtime.h>
#include <hip/hip_fp16.h>
#include <math.h>

#define KGRID 1024
#define NIMG  512
#define JW    6
#define BETAF 14.04f   // 2.34 * J
#define NB    8        // batch count (fixed by problem)
#define NBIN  16384    // 128 x 128 tiles (8x8 cells, lane=cell)
#define CAP   96       // max entries per bin (mean ~33, uniform uv)

typedef float v2f __attribute__((ext_vector_type(2)));
typedef float v4f __attribute__((ext_vector_type(4)));

// ---------- Kaiser-Bessel I0 (Abramowitz & Stegun 9.8.1 / 9.8.2, ~2e-7 rel) ----------
__device__ __forceinline__ float i0f_dev(float x) {
    float ax = fabsf(x);
    if (ax < 3.75f) {
        float z = ax * (1.0f / 3.75f);
        z = z * z;
        return 1.0f + z * (3.5156229f + z * (3.0899424f + z * (1.2067492f +
               z * (0.2659732f + z * (0.0360768f + z * 0.0045813f)))));
    } else {
        float z = 3.75f / ax;
        float p = 0.39894228f + z * (0.01328592f + z * (0.00225319f + z * (-0.00157565f +
                  z * (0.00916281f + z * (-0.02057706f + z * (0.02635537f +
                  z * (-0.01647633f + z * 0.00392377f)))))));
        return expf(ax) * rsqrtf(ax) * p;
    }
}

// ---------- Phase 0 (heterogeneous fat kernel): even blocks = BIN role,
// odd blocks = STAGE role; co-residency hides atomic/scatter latency.
// pnt line slots: [0..5]=wx*sc, [6]=packed (x0<<10)|y0 bits, [7]=0, [8..13]=wy,
// [14]=[15]=0. Entry m=M is an all-zero dummy line (pipeline padding). ----------
__global__ __launch_bounds__(256) void prep_kernel(
    const float* __restrict__ yr, const float* __restrict__ yi,
    const float* __restrict__ uv, const float* __restrict__ wts,
    float4* __restrict__ yF4, float4* __restrict__ pnt,
    int* __restrict__ cnt, int* __restrict__ list, int M)
{
    int m = (blockIdx.x >> 1) * 256 + threadIdx.x;
    if (m >= M) return;

    float u = uv[2 * m], v = uv[2 * m + 1];
    const float c2g = (float)KGRID / 6.283185307179586f;
    float kx = u * c2g, ky = v * c2g;
    float kmx = floorf(kx - 3.0f), kmy = floorf(ky - 3.0f);
    int x0m = (((int)kmx + 1) + 1024) & 1023;
    int y0m = (((int)kmy + 1) + 1024) & 1023;

    if ((blockIdx.x & 1) == 0) {
        // ---------------- BIN role ----------------
        int txA = x0m >> 3, txB = (txA + 1) & 127;
        int tyA = y0m >> 3, tyB = (tyA + 1) & 127;
        bool bx = (x0m & 7) >= 3;
        bool by = (y0m & 7) >= 3;
        int b0 = (txA << 7) | tyA;
        int b1 = (txA << 7) | tyB;
        int b2 = (txB << 7) | tyA;
        int b3 = (txB << 7) | tyB;
        int s0 = atomicAdd(&cnt[b0], 1);
        int s1 = by ? atomicAdd(&cnt[b1], 1) : -1;
        int s2 = bx ? atomicAdd(&cnt[b2], 1) : -1;
        int s3 = (bx && by) ? atomicAdd(&cnt[b3], 1) : -1;
        if ((unsigned)s0 < CAP) list[b0 * CAP + s0] = m;
        if ((unsigned)s1 < CAP) list[b1 * CAP + s1] = m;
        if ((unsigned)s2 < CAP) list[b2 * CAP + s2] = m;
        if ((unsigned)s3 < CAP) list[b3 * CAP + s3] = m;
    } else {
        // ---------------- STAGE role ----------------
        if (m == 0) {   // dummy point at index M: zero weights, zero y
            float4 z = make_float4(0.f, 0.f, 0.f, 0.f);
            #pragma unroll
            for (int q = 0; q < 4; q++) { pnt[(size_t)M * 4 + q] = z; yF4[(size_t)M * 4 + q] = z; }
        }

        float inv = 1.0f / i0f_dev(BETAF);
        float s2c = inv * inv;
        float sc = wts[m] * s2c;

        float wx[JW], wy[JW];
        #pragma unroll
        for (int j = 0; j < JW; j++) {
            float dx = kx - kmx - 1.0f - (float)j;
            float rx = dx * (1.0f / 3.0f);
            float ax = fmaxf(1.0f - rx * rx, 0.0f);
            wx[j] = i0f_dev(BETAF * sqrtf(ax)) * sc;
            float dy = ky - kmy - 1.0f - (float)j;
            float ry = dy * (1.0f / 3.0f);
            float ay = fmaxf(1.0f - ry * ry, 0.0f);
            wy[j] = i0f_dev(BETAF * sqrtf(ay));
        }

        float4* p = pnt + (size_t)m * 4;
        p[0] = make_float4(wx[0], wx[1], wx[2], wx[3]);
        p[1] = make_float4(wx[4], wx[5], __int_as_float((x0m << 10) | y0m), 0.0f);
        p[2] = make_float4(wy[0], wy[1], wy[2], wy[3]);
        p[3] = make_float4(wy[4], wy[5], 0.0f, 0.0f);

        #pragma unroll
        for (int bp = 0; bp < 4; bp++) {
            int bb = 2 * bp;
            yF4[(size_t)m * 4 + bp] = make_float4(
                yr[(size_t)bb * M + m],       yi[(size_t)bb * M + m],
                yr[(size_t)(bb + 1) * M + m], yi[(size_t)(bb + 1) * M + m]);
        }
    }
}

// ---------- Phase B: gather-gridding, PERSISTENT WAVES + dynamic ticket ----------
// 16384 one-wave tiles over 8192 wave-slots was 2 static scheduling rounds;
// Poisson(n~33, up to CAP=96) tile durations -> round-2 waves stall behind
// round-1 stragglers (Occupancy 51%). Now 2048 blocks (one resident round);
// each wave grabs tiles from a global ticket, prefetching the NEXT ticket
// before processing the current tile (grab latency hides under ~1500cy body).
__global__ __launch_bounds__(256) void grid_tile(
    const float* __restrict__ pnt1, const float4* __restrict__ yF4,
    const int* __restrict__ cnt, const int* __restrict__ list,
    int* __restrict__ ticket,
    __half2* __restrict__ gH, int M)
{
    int lane = threadIdx.x & 63;
    int lx = lane >> 3, ly = lane & 7;
    int slot = lane & 15;
    const v4f* yV = (const v4f*)yF4;

    int tnext = 0;
    if (lane == 0) tnext = atomicAdd(ticket, 1);
    tnext = __builtin_amdgcn_readfirstlane(tnext);

    while (tnext < NBIN) {
        int tile = tnext;
        if (lane == 0) tnext = atomicAdd(ticket, 1);   // prefetch next ticket
        tnext = __builtin_amdgcn_readfirstlane(tnext);

        int tx0 = (tile >> 7) << 3;
        int ty0 = (tile & 127) << 3;

        v2f acc[NB];
        #pragma unroll
        for (int b = 0; b < NB; b++) acc[b] = (v2f){0.f, 0.f};

        int n = cnt[tile]; if (n > CAP) n = CAP;
        const int* lst = list + tile * CAP;

        // preload index list into 2 VGPRs (slots beyond n -> dummy M)
        int lv0 = (lane < n) ? lst[lane] : M;
        int lv1 = (64 + lane < n && 64 + lane < CAP) ? lst[64 + lane] : M;

        #define FETCH_M(i) __builtin_amdgcn_readlane(((i) < 64) ? lv0 : lv1, (i) & 63)

        int   mA = FETCH_M(0), mB = FETCH_M(1), mC = FETCH_M(2);
        float pwA = pnt1[(size_t)mA * 16 + slot];
        float pwB = pnt1[(size_t)mB * 16 + slot];
        float pwC = pnt1[(size_t)mC * 16 + slot];
        v4f yA0 = yV[(size_t)mA * 4 + 0], yA1 = yV[(size_t)mA * 4 + 1],
            yA2 = yV[(size_t)mA * 4 + 2], yA3 = yV[(size_t)mA * 4 + 3];
        v4f yB0 = yV[(size_t)mB * 4 + 0], yB1 = yV[(size_t)mB * 4 + 1],
            yB2 = yV[(size_t)mB * 4 + 2], yB3 = yV[(size_t)mB * 4 + 3];
        v4f yC0 = yV[(size_t)mC * 4 + 0], yC1 = yV[(size_t)mC * 4 + 1],
            yC2 = yV[(size_t)mC * 4 + 2], yC3 = yV[(size_t)mC * 4 + 3];

        // process entry IDX held in (PW, Y0..Y3); then reload stage from IDX+3
        #define PROC(PW, Y0, Y1, Y2, Y3, IDX)                                      \
        {                                                                          \
            int mN = FETCH_M((IDX) + 3);                                           \
            int pwb = __float_as_int(PW);                                          \
            int meta = __builtin_amdgcn_readlane(pwb, 6);                          \
            int j1 = (tx0 + lx - (meta >> 10)) & 1023;                             \
            int j2 = (ty0 + ly - (meta & 1023)) & 1023;                            \
            int i1 = (j1 < 6) ? j1 : 15;            /* slot 15 = 0 */              \
            int i2 = (j2 < 6) ? (j2 + 8) : 14;      /* slot 14 = 0 */              \
            float wx = __int_as_float(__builtin_amdgcn_ds_bpermute(i1 << 2, pwb)); \
            float wy = __int_as_float(__builtin_amdgcn_ds_bpermute(i2 << 2, pwb)); \
            float w = wx * wy;                                                     \
            v2f w2 = {w, w};                                                       \
            acc[0] = __builtin_elementwise_fma(w2, Y0.xy, acc[0]);                 \
            acc[1] = __builtin_elementwise_fma(w2, Y0.zw, acc[1]);                 \
            acc[2] = __builtin_elementwise_fma(w2, Y1.xy, acc[2]);                 \
            acc[3] = __builtin_elementwise_fma(w2, Y1.zw, acc[3]);                 \
            acc[4] = __builtin_elementwise_fma(w2, Y2.xy, acc[4]);                 \
            acc[5] = __builtin_elementwise_fma(w2, Y2.zw, acc[5]);                 \
            acc[6] = __builtin_elementwise_fma(w2, Y3.xy, acc[6]);                 \
            acc[7] = __builtin_elementwise_fma(w2, Y3.zw, acc[7]);                 \
            PW = pnt1[(size_t)mN * 16 + slot];                                     \
            Y0 = yV[(size_t)mN * 4 + 0];                                           \
            Y1 = yV[(size_t)mN * 4 + 1];                                           \
            Y2 = yV[(size_t)mN * 4 + 2];                                           \
            Y3 = yV[(size_t)mN * 4 + 3];                                           \
        }

        for (int i = 0; i < n; i += 3) {
            PROC(pwA, yA0, yA1, yA2, yA3, i);
            PROC(pwB, yB0, yB1, yB2, yB3, i + 1);
            PROC(pwC, yC0, yC1, yC2, yC3, i + 2);
        }
        #undef PROC
        #undef FETCH_M

        // flush fp16: tiles partition the grid -> every cell written exactly once
        size_t cell = ((size_t)(tx0 + lx) << 10) + (size_t)(ty0 + ly);
        #pragma unroll
        for (int b = 0; b < NB; b++)
            gH[((size_t)b << 20) + cell] = __float22half2_rn(make_float2(acc[b].x, acc[b].y));
    }
}

// ---------- LDS index swizzle: phys = idx ^ ((idx>>4)&15) (involution).
// Note SW(i+1024) == SW(i)+1024: second FFT row is a clean +1024 offset. ----------
#define SW(i) ((i) ^ (((i) >> 4) & 15))

// ---------- DUAL Stockham radix-4 1024-pt inverse FFT in LDS ----------
// Two independent FFTs per barrier interval (rows at offset 0 and +1024).
// 5 stages; result lands in Y: call sites read Bb.
__device__ __forceinline__ void fft1024_inv2(float2* X, float2* Y, const float2* W, int tid)
{
    float2* src = X;
    float2* dst = Y;
    #pragma unroll
    for (int stage = 0; stage < 5; stage++) {
        const int s = 1 << (2 * stage);   // 1,4,16,64,256
        __syncthreads();
        int t = tid;
        int a = t & ~(s - 1);
        float2 x0 = src[SW(t)];
        float2 x1 = src[SW(t + 256)];
        float2 x2 = src[SW(t + 512)];
        float2 x3 = src[SW(t + 768)];
        float2 u0 = src[SW(t) + 1024];
        float2 u1 = src[SW(t + 256) + 1024];
        float2 u2 = src[SW(t + 512) + 1024];
        float2 u3 = src[SW(t + 768) + 1024];
        float2 w1 = W[a];
        float2 w2 = W[2 * a];
        float2 w3 = make_float2(w1.x * w2.x - w1.y * w2.y,
                                w1.x * w2.y + w1.y * w2.x);
        int ob = 3 * a + t;
        // row 0
        {
            float2 d0 = make_float2(x0.x + x2.x, x0.y + x2.y);
            float2 e0 = make_float2(x0.x - x2.x, x0.y - x2.y);
            float2 d1 = make_float2(x1.x + x3.x, x1.y + x3.y);
            float2 e1 = make_float2(-(x1.y - x3.y), x1.x - x3.x);
            float2 s0 = make_float2(d0.x + d1.x, d0.y + d1.y);
            float2 s1 = make_float2(e0.x + e1.x, e0.y + e1.y);
            float2 s2 = make_float2(d0.x - d1.x, d0.y - d1.y);
            float2 s3 = make_float2(e0.x - e1.x, e0.y - e1.y);
            dst[SW(ob)]         = s0;
            dst[SW(ob + s)]     = make_float2(w1.x * s1.x - w1.y * s1.y,
                                              w1.x * s1.y + w1.y * s1.x);
            dst[SW(ob + 2 * s)] = make_float2(w2.x * s2.x - w2.y * s2.y,
                                              w2.x * s2.y + w2.y * s2.x);
            dst[SW(ob + 3 * s)] = make_float2(w3.x * s3.x - w3.y * s3.y,
                                              w3.x * s3.y + w3.y * s3.x);
        }
        // row 1
        {
            float2 d0 = make_float2(u0.x + u2.x, u0.y + u2.y);
            float2 e0 = make_float2(u0.x - u2.x, u0.y - u2.y);
            float2 d1 = make_float2(u1.x + u3.x, u1.y + u3.y);
            float2 e1 = make_float2(-(u1.y - u3.y), u1.x - u3.x);
            float2 s0 = make_float2(d0.x + d1.x, d0.y + d1.y);
            float2 s1 = make_float2(e0.x + e1.x, e0.y + e1.y);
            float2 s2 = make_float2(d0.x - d1.x, d0.y - d1.y);
            float2 s3 = make_float2(e0.x - e1.x, e0.y - e1.y);
            dst[SW(ob) + 1024]         = s0;
            dst[SW(ob + s) + 1024]     = make_float2(w1.x * s1.x - w1.y * s1.y,
                                                     w1.x * s1.y + w1.y * s1.x);
            dst[SW(ob + 2 * s) + 1024] = make_float2(w2.x * s2.x - w2.y * s2.y,
                                                     w2.x * s2.y + w2.y * s2.x);
            dst[SW(ob + 3 * s) + 1024] = make_float2(w3.x * s3.x - w3.y * s3.y,
                                                     w3.x * s3.y + w3.y * s3.x);
        }
        float2* tmp = src; src = dst; dst = tmp;
    }
    __syncthreads();
}

// ---------- Pass 1 (fused Hermitian pack, mirror-paired): rows k2 -> x2 ----------
// Block g handles 8 output rows as 4 DUAL-FFT pairs: (4g+f, 1020-4g+f).
__global__ __launch_bounds__(256) void fft_pass1(const __half2* __restrict__ gH,
                                                 __half2* __restrict__ T)
{
    __shared__ float2 A[2048];
    __shared__ float2 Bb[2048];
    __shared__ float2 W[512];
    __shared__ __half2 R[8][512];

    int blk = blockIdx.x;
    int p   = blk >> 7;          // 4 packed plane-pairs
    int g   = blk & 127;
    int tid = threadIdx.x;

    #pragma unroll
    for (int h = 0; h < 2; h++) {
        int j = tid + (h << 8);
        float sn, cn;
        __sincosf(6.283185307179586f * (float)j * (1.0f / 1024.0f), &sn, &cn);
        W[j] = make_float2(cn, sn);
    }

    const __half2* gA = gH + ((size_t)(2 * p)     << 20);
    const __half2* gB = gH + ((size_t)(2 * p + 1) << 20);

    for (int f = 0; f < 4; f++) {
        int k1a  = 4 * g + f;
        int k1b  = 1020 - 4 * g + f;
        int nk1a = (1024 - k1a) & 1023;
        int nk1b = (1024 - k1b) & 1023;
        const __half2* rAa  = gA + ((size_t)k1a  << 10);
        const __half2* rAan = gA + ((size_t)nk1a << 10);
        const __half2* rBa  = gB + ((size_t)k1a  << 10);
        const __half2* rBan = gB + ((size_t)nk1a << 10);
        const __half2* rAb  = gA + ((size_t)k1b  << 10);
        const __half2* rAbn = gA + ((size_t)nk1b << 10);
        const __half2* rBb  = gB + ((size_t)k1b  << 10);
        const __half2* rBbn = gB + ((size_t)nk1b << 10);
        __syncthreads();
        #pragma unroll
        for (int h = 0; h < 4; h++) {
            int k2  = tid + (h << 8);
            int nk2 = (1024 - k2) & 1023;
            float2 va  = __half22float2(rAa[k2]);
            float2 van = __half22float2(rAan[nk2]);
            float2 vb  = __half22float2(rBa[k2]);
            float2 vbn = __half22float2(rBan[nk2]);
            A[SW(k2)] = make_float2(0.5f * (va.x + van.x) - 0.5f * (vb.y - vbn.y),
                                    0.5f * (va.y - van.y) + 0.5f * (vb.x + vbn.x));
            float2 vc  = __half22float2(rAb[k2]);
            float2 vcn = __half22float2(rAbn[nk2]);
            float2 vd  = __half22float2(rBb[k2]);
            float2 vdn = __half22float2(rBbn[nk2]);
            A[SW(k2) + 1024] = make_float2(0.5f * (vc.x + vcn.x) - 0.5f * (vd.y - vdn.y),
                                           0.5f * (vc.y - vcn.y) + 0.5f * (vd.x + vdn.x));
        }
        fft1024_inv2(A, Bb, W, tid);
        #pragma unroll
        for (int h = 0; h < 2; h++) {
            int xo2 = tid + (h << 8);
            int sidx = SW((xo2 + 768) & 1023);
            R[f][xo2]     = __float22half2_rn(Bb[sidx]);
            R[f + 4][xo2] = __float22half2_rn(Bb[sidx + 1024]);
        }
    }
    __syncthreads();

    // T layout: half2 T[p][xo2][k1]; both quads contiguous -> 16B stores
    #pragma unroll
    for (int h = 0; h < 2; h++) {
        int xo2 = tid + (h << 8);
        __half2* Trow = T + (((size_t)p * 512 + xo2) << 10);
        int4 q0, q1;
        q0.x = *(const int*)&R[0][xo2]; q0.y = *(const int*)&R[1][xo2];
        q0.z = *(const int*)&R[2][xo2]; q0.w = *(const int*)&R[3][xo2];
        q1.x = *(const int*)&R[4][xo2]; q1.y = *(const int*)&R[5][xo2];
        q1.z = *(const int*)&R[6][xo2]; q1.w = *(const int*)&R[7][xo2];
        *(int4*)(Trow + 4 * g)          = q0;
        *(int4*)(Trow + (1020 - 4 * g)) = q1;
    }
}

// ---------- de-apodization (matches _deapod) ----------
__device__ __forceinline__ float apodf(int n) {
    float x  = ((float)n - 256.0f) * (1.0f / 1024.0f);
    float px = 3.14159265358979f * 6.0f * x;
    float t  = BETAF * BETAF - px * px;
    float st = sqrtf(fabsf(t));
    float num = (t > 0.0f) ? sinhf(st) : __sinf(st);
    return num / fmaxf(st, 1e-6f);
}

// ---------- Pass 2: columns (k1 -> x1) of packed planes, 4 cols/block as
// 2 DUAL-FFT pairs; real -> batch 2p, imag -> batch 2p+1; float4 stores ----------
__global__ __launch_bounds__(256) void fft_pass2(const __half2* __restrict__ T,
                                                 float* __restrict__ out)
{
    __shared__ float2 A[2048];
    __shared__ float2 Bb[2048];
    __shared__ float2 W[512];
    __shared__ float2 R[4][512];

    int blk = blockIdx.x;
    int p   = blk >> 7;
    int xg  = blk & 127;
    int tid = threadIdx.x;

    #pragma unroll
    for (int h = 0; h < 2; h++) {
        int j = tid + (h << 8);
        float sn, cn;
        __sincosf(6.283185307179586f * (float)j * (1.0f / 1024.0f), &sn, &cn);
        W[j] = make_float2(cn, sn);
    }

    float a2[4];
    #pragma unroll
    for (int r = 0; r < 4; r++) a2[r] = apodf((xg << 2) + r);

    for (int r = 0; r < 2; r++) {
        int xo2a = (xg << 2) + 2 * r;
        int xo2b = xo2a + 1;
        const __half2* rowA = T + (((size_t)p * 512 + xo2a) << 10);
        const __half2* rowB = T + (((size_t)p * 512 + xo2b) << 10);
        __syncthreads();
        #pragma unroll
        for (int h = 0; h < 4; h++) {
            int i = tid + (h << 8);
            A[SW(i)]        = __half22float2(rowA[i]);
            A[SW(i) + 1024] = __half22float2(rowB[i]);
        }
        fft1024_inv2(A, Bb, W, tid);
        #pragma unroll
        for (int h = 0; h < 2; h++) {
            int xo1 = tid + (h << 8);
            int sidx = SW((xo1 + 768) & 1023);
            float2 v0 = Bb[sidx];
            float2 v1 = Bb[sidx + 1024];
            R[2 * r][xo1]     = make_float2(v0.x / a2[2 * r],     v0.y / a2[2 * r]);
            R[2 * r + 1][xo1] = make_float2(v1.x / a2[2 * r + 1], v1.y / a2[2 * r + 1]);
        }
    }
    __syncthreads();

    int b0 = 2 * p;
    #pragma unroll
    for (int h = 0; h < 2; h++) {
        int xo1 = tid + (h << 8);
        float inva1 = 1.0f / apodf(xo1);
        float2 f0 = R[0][xo1], f1 = R[1][xo1], f2 = R[2][xo1], f3 = R[3][xo1];
        float4* o0 = (float4*)(out + (((size_t)b0 * 512 + xo1) << 9) + (xg << 2));
        float4* o1 = (float4*)(out + (((size_t)(b0 + 1) * 512 + xo1) << 9) + (xg << 2));
        *o0 = make_float4(f0.x * inva1, f1.x * inva1, f2.x * inva1, f3.x * inva1);
        *o1 = make_float4(f0.y * inva1, f1.y * inva1, f2.y * inva1, f3.y * inva1);
    }
}

// ---------- host launch ----------
extern "C" void kernel_launch(void* const* d_in, const int* in_sizes, int n_in,
                              void* d_out, int out_size, void* d_ws, size_t ws_size,
                              hipStream_t stream)
{
    const float* yr  = (const float*)d_in[0];
    const float* yi  = (const float*)d_in[1];
    const float* uv  = (const float*)d_in[2];
    const float* wts = (const float*)d_in[3];

    int M = in_sizes[3];

    // ws layout (non-overlapping):
    //  [0,32)MB : gH (8 fp16 planar grids, 4 MB each)
    //  [32,40)MB: T (fp16, 8 MB)
    //  [64,96)MB: prep/grid scratch (cnt | ticket | list | yF4 | pnt)
    __half2* gH = (__half2*)d_ws;
    __half2* T  = (__half2*)((char*)d_ws + ((size_t)32 << 20));
    char*    p2 = (char*)d_ws + ((size_t)64 << 20);
    int*    cnt    = (int*)p2;                                   // 64 KB
    int*    ticket = (int*)(p2 + 65536);                         // 256 B pad
    int*    list   = (int*)(p2 + 65792);                         // 6.29 MB (ends < 6.55 MB)
    float4* yF4  = (float4*)(p2 + 6553600);                      // 12.8 MB (M+1 pts)
    float4* pnt  = (float4*)(p2 + 19500032);                     // 12.8 MB (M+1 pts)

    hipMemsetAsync(cnt, 0, 65536 + 256, stream);   // cnt + ticket
    int nb = (M + 255) / 256;
    prep_kernel<<<dim3(2 * nb), dim3(256), 0, stream>>>(
        yr, yi, uv, wts, yF4, pnt, cnt, list, M);
    grid_tile<<<dim3(2048), dim3(256), 0, stream>>>(
        (const float*)pnt, (const float4*)yF4, cnt, list, ticket, gH, M);
    fft_pass1<<<dim3(4 * 128), dim3(256), 0, stream>>>(gH, T);
    fft_pass2<<<dim3(4 * 128), dim3(256), 0, stream>>>(T, (float*)d_out);
}

// Round 15
// 159.996 us; speedup vs baseline: 2.6497x; 2.6497x over previous
//
#include <hip/hip_runtime.h>
#include <hip/hip_fp16.h>
#include <math.h>

#define KGRID 1024
#define NIMG  512
#define JW    6
#define BETAF 14.04f   // 2.34 * J
#define NB    8        // batch count (fixed by problem)
#define NBIN  16384    // 128 x 128 tiles (8x8 cells, lane=cell)
#define CAP   96       // max entries per bin (mean ~33, uniform uv)

typedef float v2f __attribute__((ext_vector_type(2)));
typedef float v4f __attribute__((ext_vector_type(4)));

// ---------- Kaiser-Bessel I0 (Abramowitz & Stegun 9.8.1 / 9.8.2, ~2e-7 rel) ----------
__device__ __forceinline__ float i0f_dev(float x) {
    float ax = fabsf(x);
    if (ax < 3.75f) {
        float z = ax * (1.0f / 3.75f);
        z = z * z;
        return 1.0f + z * (3.5156229f + z * (3.0899424f + z * (1.2067492f +
               z * (0.2659732f + z * (0.0360768f + z * 0.0045813f)))));
    } else {
        float z = 3.75f / ax;
        float p = 0.39894228f + z * (0.01328592f + z * (0.00225319f + z * (-0.00157565f +
                  z * (0.00916281f + z * (-0.02057706f + z * (0.02635537f +
                  z * (-0.01647633f + z * 0.00392377f)))))));
        return expf(ax) * rsqrtf(ax) * p;
    }
}

// ---------- Phase 0 (heterogeneous fat kernel): even blocks = BIN role,
// odd blocks = STAGE role; co-residency hides atomic/scatter latency.
// pnt line slots: [0..5]=wx*sc, [6]=packed (x0<<10)|y0 bits, [7]=0, [8..13]=wy,
// [14]=[15]=0. Entry m=M is an all-zero dummy line (pipeline padding). ----------
__global__ __launch_bounds__(256) void prep_kernel(
    const float* __restrict__ yr, const float* __restrict__ yi,
    const float* __restrict__ uv, const float* __restrict__ wts,
    float4* __restrict__ yF4, float4* __restrict__ pnt,
    int* __restrict__ cnt, int* __restrict__ list, int M)
{
    int m = (blockIdx.x >> 1) * 256 + threadIdx.x;
    if (m >= M) return;

    float u = uv[2 * m], v = uv[2 * m + 1];
    const float c2g = (float)KGRID / 6.283185307179586f;
    float kx = u * c2g, ky = v * c2g;
    float kmx = floorf(kx - 3.0f), kmy = floorf(ky - 3.0f);
    int x0m = (((int)kmx + 1) + 1024) & 1023;
    int y0m = (((int)kmy + 1) + 1024) & 1023;

    if ((blockIdx.x & 1) == 0) {
        // ---------------- BIN role ----------------
        int txA = x0m >> 3, txB = (txA + 1) & 127;
        int tyA = y0m >> 3, tyB = (tyA + 1) & 127;
        bool bx = (x0m & 7) >= 3;
        bool by = (y0m & 7) >= 3;
        int b0 = (txA << 7) | tyA;
        int b1 = (txA << 7) | tyB;
        int b2 = (txB << 7) | tyA;
        int b3 = (txB << 7) | tyB;
        int s0 = atomicAdd(&cnt[b0], 1);
        int s1 = by ? atomicAdd(&cnt[b1], 1) : -1;
        int s2 = bx ? atomicAdd(&cnt[b2], 1) : -1;
        int s3 = (bx && by) ? atomicAdd(&cnt[b3], 1) : -1;
        if ((unsigned)s0 < CAP) list[b0 * CAP + s0] = m;
        if ((unsigned)s1 < CAP) list[b1 * CAP + s1] = m;
        if ((unsigned)s2 < CAP) list[b2 * CAP + s2] = m;
        if ((unsigned)s3 < CAP) list[b3 * CAP + s3] = m;
    } else {
        // ---------------- STAGE role ----------------
        if (m == 0) {   // dummy point at index M: zero weights, zero y
            float4 z = make_float4(0.f, 0.f, 0.f, 0.f);
            #pragma unroll
            for (int q = 0; q < 4; q++) { pnt[(size_t)M * 4 + q] = z; yF4[(size_t)M * 4 + q] = z; }
        }

        float inv = 1.0f / i0f_dev(BETAF);
        float s2c = inv * inv;
        float sc = wts[m] * s2c;

        float wx[JW], wy[JW];
        #pragma unroll
        for (int j = 0; j < JW; j++) {
            float dx = kx - kmx - 1.0f - (float)j;
            float rx = dx * (1.0f / 3.0f);
            float ax = fmaxf(1.0f - rx * rx, 0.0f);
            wx[j] = i0f_dev(BETAF * sqrtf(ax)) * sc;
            float dy = ky - kmy - 1.0f - (float)j;
            float ry = dy * (1.0f / 3.0f);
            float ay = fmaxf(1.0f - ry * ry, 0.0f);
            wy[j] = i0f_dev(BETAF * sqrtf(ay));
        }

        float4* p = pnt + (size_t)m * 4;
        p[0] = make_float4(wx[0], wx[1], wx[2], wx[3]);
        p[1] = make_float4(wx[4], wx[5], __int_as_float((x0m << 10) | y0m), 0.0f);
        p[2] = make_float4(wy[0], wy[1], wy[2], wy[3]);
        p[3] = make_float4(wy[4], wy[5], 0.0f, 0.0f);

        #pragma unroll
        for (int bp = 0; bp < 4; bp++) {
            int bb = 2 * bp;
            yF4[(size_t)m * 4 + bp] = make_float4(
                yr[(size_t)bb * M + m],       yi[(size_t)bb * M + m],
                yr[(size_t)(bb + 1) * M + m], yi[(size_t)(bb + 1) * M + m]);
        }
    }
}

// ---------- Phase B: gather-gridding, lane=cell, register accumulation ----------
// One wave per 8x8 tile; acc fp32 (packed v2f -> v_pk_fma_f32), flush fp16.
// Loop unrolled 3x with statically-named pipeline stages A/B/C (no rotation
// movs); m via readlane -> SGPR -> wave-uniform s_load for pnt/y lines.
// Overrun past n (up to 2 entries) hits the all-zero dummy line -> w = 0.
// NOTE (R14): HW block scheduling already load-balances the 4096 blocks;
// dynamic ticket queue regressed 8.5x (atomic in loop-carried chain).
__global__ __launch_bounds__(256) void grid_tile(
    const float* __restrict__ pnt1, const float4* __restrict__ yF4,
    const int* __restrict__ cnt, const int* __restrict__ list,
    __half2* __restrict__ gH, int M)
{
    int lane = threadIdx.x & 63;
    int wid  = threadIdx.x >> 6;
    int tile = blockIdx.x * 4 + wid;
    int tx0 = (tile >> 7) << 3;
    int ty0 = (tile & 127) << 3;
    int lx = lane >> 3, ly = lane & 7;
    int slot = lane & 15;

    v2f acc[NB];
    #pragma unroll
    for (int b = 0; b < NB; b++) acc[b] = (v2f){0.f, 0.f};

    int n = cnt[tile]; if (n > CAP) n = CAP;
    const int* lst = list + tile * CAP;
    const v4f* yV = (const v4f*)yF4;

    // preload index list into 2 VGPRs (slots beyond n -> dummy M)
    int lv0 = (lane < n) ? lst[lane] : M;
    int lv1 = (64 + lane < n && 64 + lane < CAP) ? lst[64 + lane] : M;

    #define FETCH_M(i) __builtin_amdgcn_readlane(((i) < 64) ? lv0 : lv1, (i) & 63)

    int   mA = FETCH_M(0), mB = FETCH_M(1), mC = FETCH_M(2);
    float pwA = pnt1[(size_t)mA * 16 + slot];
    float pwB = pnt1[(size_t)mB * 16 + slot];
    float pwC = pnt1[(size_t)mC * 16 + slot];
    v4f yA0 = yV[(size_t)mA * 4 + 0], yA1 = yV[(size_t)mA * 4 + 1],
        yA2 = yV[(size_t)mA * 4 + 2], yA3 = yV[(size_t)mA * 4 + 3];
    v4f yB0 = yV[(size_t)mB * 4 + 0], yB1 = yV[(size_t)mB * 4 + 1],
        yB2 = yV[(size_t)mB * 4 + 2], yB3 = yV[(size_t)mB * 4 + 3];
    v4f yC0 = yV[(size_t)mC * 4 + 0], yC1 = yV[(size_t)mC * 4 + 1],
        yC2 = yV[(size_t)mC * 4 + 2], yC3 = yV[(size_t)mC * 4 + 3];

    // process entry IDX held in (PW, Y0..Y3); then reload stage from IDX+3
    #define PROC(PW, Y0, Y1, Y2, Y3, IDX)                                          \
    {                                                                              \
        int mN = FETCH_M((IDX) + 3);                                               \
        int pwb = __float_as_int(PW);                                              \
        int meta = __builtin_amdgcn_readlane(pwb, 6);                              \
        int j1 = (tx0 + lx - (meta >> 10)) & 1023;                                 \
        int j2 = (ty0 + ly - (meta & 1023)) & 1023;                                 \
        int i1 = (j1 < 6) ? j1 : 15;            /* slot 15 = 0 */                  \
        int i2 = (j2 < 6) ? (j2 + 8) : 14;      /* slot 14 = 0 */                  \
        float wx = __int_as_float(__builtin_amdgcn_ds_bpermute(i1 << 2, pwb));     \
        float wy = __int_as_float(__builtin_amdgcn_ds_bpermute(i2 << 2, pwb));     \
        float w = wx * wy;                                                         \
        v2f w2 = {w, w};                                                           \
        acc[0] = __builtin_elementwise_fma(w2, Y0.xy, acc[0]);                     \
        acc[1] = __builtin_elementwise_fma(w2, Y0.zw, acc[1]);                     \
        acc[2] = __builtin_elementwise_fma(w2, Y1.xy, acc[2]);                     \
        acc[3] = __builtin_elementwise_fma(w2, Y1.zw, acc[3]);                     \
        acc[4] = __builtin_elementwise_fma(w2, Y2.xy, acc[4]);                     \
        acc[5] = __builtin_elementwise_fma(w2, Y2.zw, acc[5]);                     \
        acc[6] = __builtin_elementwise_fma(w2, Y3.xy, acc[6]);                     \
        acc[7] = __builtin_elementwise_fma(w2, Y3.zw, acc[7]);                     \
        PW = pnt1[(size_t)mN * 16 + slot];                                         \
        Y0 = yV[(size_t)mN * 4 + 0];                                               \
        Y1 = yV[(size_t)mN * 4 + 1];                                               \
        Y2 = yV[(size_t)mN * 4 + 2];                                               \
        Y3 = yV[(size_t)mN * 4 + 3];                                               \
    }

    for (int i = 0; i < n; i += 3) {
        PROC(pwA, yA0, yA1, yA2, yA3, i);
        PROC(pwB, yB0, yB1, yB2, yB3, i + 1);
        PROC(pwC, yC0, yC1, yC2, yC3, i + 2);
    }
    #undef PROC
    #undef FETCH_M

    // flush fp16: tiles partition the grid -> every cell written exactly once
    size_t cell = ((size_t)(tx0 + lx) << 10) + (size_t)(ty0 + ly);
    #pragma unroll
    for (int b = 0; b < NB; b++)
        gH[((size_t)b << 20) + cell] = __float22half2_rn(make_float2(acc[b].x, acc[b].y));
}

// ---------- LDS index swizzle: phys = idx ^ ((idx>>4)&15) (involution).
// Note SW(i+1024) == SW(i)+1024: second FFT row is a clean +1024 offset. ----------
#define SW(i) ((i) ^ (((i) >> 4) & 15))

// ---------- DUAL Stockham radix-4 1024-pt inverse FFT in LDS ----------
// Two independent FFTs per barrier interval (rows at offset 0 and +1024).
// 5 stages; result lands in Y: call sites read Bb.
__device__ __forceinline__ void fft1024_inv2(float2* X, float2* Y, const float2* W, int tid)
{
    float2* src = X;
    float2* dst = Y;
    #pragma unroll
    for (int stage = 0; stage < 5; stage++) {
        const int s = 1 << (2 * stage);   // 1,4,16,64,256
        __syncthreads();
        int t = tid;
        int a = t & ~(s - 1);
        float2 x0 = src[SW(t)];
        float2 x1 = src[SW(t + 256)];
        float2 x2 = src[SW(t + 512)];
        float2 x3 = src[SW(t + 768)];
        float2 u0 = src[SW(t) + 1024];
        float2 u1 = src[SW(t + 256) + 1024];
        float2 u2 = src[SW(t + 512) + 1024];
        float2 u3 = src[SW(t + 768) + 1024];
        float2 w1 = W[a];
        float2 w2 = W[2 * a];
        float2 w3 = make_float2(w1.x * w2.x - w1.y * w2.y,
                                w1.x * w2.y + w1.y * w2.x);
        int ob = 3 * a + t;
        // row 0
        {
            float2 d0 = make_float2(x0.x + x2.x, x0.y + x2.y);
            float2 e0 = make_float2(x0.x - x2.x, x0.y - x2.y);
            float2 d1 = make_float2(x1.x + x3.x, x1.y + x3.y);
            float2 e1 = make_float2(-(x1.y - x3.y), x1.x - x3.x);
            float2 s0 = make_float2(d0.x + d1.x, d0.y + d1.y);
            float2 s1 = make_float2(e0.x + e1.x, e0.y + e1.y);
            float2 s2 = make_float2(d0.x - d1.x, d0.y - d1.y);
            float2 s3 = make_float2(e0.x - e1.x, e0.y - e1.y);
            dst[SW(ob)]         = s0;
            dst[SW(ob + s)]     = make_float2(w1.x * s1.x - w1.y * s1.y,
                                              w1.x * s1.y + w1.y * s1.x);
            dst[SW(ob + 2 * s)] = make_float2(w2.x * s2.x - w2.y * s2.y,
                                              w2.x * s2.y + w2.y * s2.x);
            dst[SW(ob + 3 * s)] = make_float2(w3.x * s3.x - w3.y * s3.y,
                                              w3.x * s3.y + w3.y * s3.x);
        }
        // row 1
        {
            float2 d0 = make_float2(u0.x + u2.x, u0.y + u2.y);
            float2 e0 = make_float2(u0.x - u2.x, u0.y - u2.y);
            float2 d1 = make_float2(u1.x + u3.x, u1.y + u3.y);
            float2 e1 = make_float2(-(u1.y - u3.y), u1.x - u3.x);
            float2 s0 = make_float2(d0.x + d1.x, d0.y + d1.y);
            float2 s1 = make_float2(e0.x + e1.x, e0.y + e1.y);
            float2 s2 = make_float2(d0.x - d1.x, d0.y - d1.y);
            float2 s3 = make_float2(e0.x - e1.x, e0.y - e1.y);
            dst[SW(ob) + 1024]         = s0;
            dst[SW(ob + s) + 1024]     = make_float2(w1.x * s1.x - w1.y * s1.y,
                                                     w1.x * s1.y + w1.y * s1.x);
            dst[SW(ob + 2 * s) + 1024] = make_float2(w2.x * s2.x - w2.y * s2.y,
                                                     w2.x * s2.y + w2.y * s2.x);
            dst[SW(ob + 3 * s) + 1024] = make_float2(w3.x * s3.x - w3.y * s3.y,
                                                     w3.x * s3.y + w3.y * s3.x);
        }
        float2* tmp = src; src = dst; dst = tmp;
    }
    __syncthreads();
}

// ---------- Pass 1 (fused Hermitian pack, mirror-paired): rows k2 -> x2 ----------
// Block g handles 8 output rows as 4 DUAL-FFT pairs: (4g+f, 1020-4g+f).
__global__ __launch_bounds__(256) void fft_pass1(const __half2* __restrict__ gH,
                                                 __half2* __restrict__ T)
{
    __shared__ float2 A[2048];
    __shared__ float2 Bb[2048];
    __shared__ float2 W[512];
    __shared__ __half2 R[8][512];

    int blk = blockIdx.x;
    int p   = blk >> 7;          // 4 packed plane-pairs
    int g   = blk & 127;
    int tid = threadIdx.x;

    #pragma unroll
    for (int h = 0; h < 2; h++) {
        int j = tid + (h << 8);
        float sn, cn;
        __sincosf(6.283185307179586f * (float)j * (1.0f / 1024.0f), &sn, &cn);
        W[j] = make_float2(cn, sn);
    }

    const __half2* gA = gH + ((size_t)(2 * p)     << 20);
    const __half2* gB = gH + ((size_t)(2 * p + 1) << 20);

    for (int f = 0; f < 4; f++) {
        int k1a  = 4 * g + f;
        int k1b  = 1020 - 4 * g + f;
        int nk1a = (1024 - k1a) & 1023;
        int nk1b = (1024 - k1b) & 1023;
        const __half2* rAa  = gA + ((size_t)k1a  << 10);
        const __half2* rAan = gA + ((size_t)nk1a << 10);
        const __half2* rBa  = gB + ((size_t)k1a  << 10);
        const __half2* rBan = gB + ((size_t)nk1a << 10);
        const __half2* rAb  = gA + ((size_t)k1b  << 10);
        const __half2* rAbn = gA + ((size_t)nk1b << 10);
        const __half2* rBb  = gB + ((size_t)k1b  << 10);
        const __half2* rBbn = gB + ((size_t)nk1b << 10);
        __syncthreads();
        #pragma unroll
        for (int h = 0; h < 4; h++) {
            int k2  = tid + (h << 8);
            int nk2 = (1024 - k2) & 1023;
            float2 va  = __half22float2(rAa[k2]);
            float2 van = __half22float2(rAan[nk2]);
            float2 vb  = __half22float2(rBa[k2]);
            float2 vbn = __half22float2(rBan[nk2]);
            A[SW(k2)] = make_float2(0.5f * (va.x + van.x) - 0.5f * (vb.y - vbn.y),
                                    0.5f * (va.y - van.y) + 0.5f * (vb.x + vbn.x));
            float2 vc  = __half22float2(rAb[k2]);
            float2 vcn = __half22float2(rAbn[nk2]);
            float2 vd  = __half22float2(rBb[k2]);
            float2 vdn = __half22float2(rBbn[nk2]);
            A[SW(k2) + 1024] = make_float2(0.5f * (vc.x + vcn.x) - 0.5f * (vd.y - vdn.y),
                                           0.5f * (vc.y - vcn.y) + 0.5f * (vd.x + vdn.x));
        }
        fft1024_inv2(A, Bb, W, tid);
        #pragma unroll
        for (int h = 0; h < 2; h++) {
            int xo2 = tid + (h << 8);
            int sidx = SW((xo2 + 768) & 1023);
            R[f][xo2]     = __float22half2_rn(Bb[sidx]);
            R[f + 4][xo2] = __float22half2_rn(Bb[sidx + 1024]);
        }
    }
    __syncthreads();

    // T layout: half2 T[p][xo2][k1]; both quads contiguous -> 16B stores
    #pragma unroll
    for (int h = 0; h < 2; h++) {
        int xo2 = tid + (h << 8);
        __half2* Trow = T + (((size_t)p * 512 + xo2) << 10);
        int4 q0, q1;
        q0.x = *(const int*)&R[0][xo2]; q0.y = *(const int*)&R[1][xo2];
        q0.z = *(const int*)&R[2][xo2]; q0.w = *(const int*)&R[3][xo2];
        q1.x = *(const int*)&R[4][xo2]; q1.y = *(const int*)&R[5][xo2];
        q1.z = *(const int*)&R[6][xo2]; q1.w = *(const int*)&R[7][xo2];
        *(int4*)(Trow + 4 * g)          = q0;
        *(int4*)(Trow + (1020 - 4 * g)) = q1;
    }
}

// ---------- de-apodization (matches _deapod) ----------
__device__ __forceinline__ float apodf(int n) {
    float x  = ((float)n - 256.0f) * (1.0f / 1024.0f);
    float px = 3.14159265358979f * 6.0f * x;
    float t  = BETAF * BETAF - px * px;
    float st = sqrtf(fabsf(t));
    float num = (t > 0.0f) ? sinhf(st) : __sinf(st);
    return num / fmaxf(st, 1e-6f);
}

// ---------- Pass 2: columns (k1 -> x1) of packed planes, 4 cols/block as
// 2 DUAL-FFT pairs; real -> batch 2p, imag -> batch 2p+1; float4 stores ----------
__global__ __launch_bounds__(256) void fft_pass2(const __half2* __restrict__ T,
                                                 float* __restrict__ out)
{
    __shared__ float2 A[2048];
    __shared__ float2 Bb[2048];
    __shared__ float2 W[512];
    __shared__ float2 R[4][512];

    int blk = blockIdx.x;
    int p   = blk >> 7;
    int xg  = blk & 127;
    int tid = threadIdx.x;

    #pragma unroll
    for (int h = 0; h < 2; h++) {
        int j = tid + (h << 8);
        float sn, cn;
        __sincosf(6.283185307179586f * (float)j * (1.0f / 1024.0f), &sn, &cn);
        W[j] = make_float2(cn, sn);
    }

    float a2[4];
    #pragma unroll
    for (int r = 0; r < 4; r++) a2[r] = apodf((xg << 2) + r);

    for (int r = 0; r < 2; r++) {
        int xo2a = (xg << 2) + 2 * r;
        int xo2b = xo2a + 1;
        const __half2* rowA = T + (((size_t)p * 512 + xo2a) << 10);
        const __half2* rowB = T + (((size_t)p * 512 + xo2b) << 10);
        __syncthreads();
        #pragma unroll
        for (int h = 0; h < 4; h++) {
            int i = tid + (h << 8);
            A[SW(i)]        = __half22float2(rowA[i]);
            A[SW(i) + 1024] = __half22float2(rowB[i]);
        }
        fft1024_inv2(A, Bb, W, tid);
        #pragma unroll
        for (int h = 0; h < 2; h++) {
            int xo1 = tid + (h << 8);
            int sidx = SW((xo1 + 768) & 1023);
            float2 v0 = Bb[sidx];
            float2 v1 = Bb[sidx + 1024];
            R[2 * r][xo1]     = make_float2(v0.x / a2[2 * r],     v0.y / a2[2 * r]);
            R[2 * r + 1][xo1] = make_float2(v1.x / a2[2 * r + 1], v1.y / a2[2 * r + 1]);
        }
    }
    __syncthreads();

    int b0 = 2 * p;
    #pragma unroll
    for (int h = 0; h < 2; h++) {
        int xo1 = tid + (h << 8);
        float inva1 = 1.0f / apodf(xo1);
        float2 f0 = R[0][xo1], f1 = R[1][xo1], f2 = R[2][xo1], f3 = R[3][xo1];
        float4* o0 = (float4*)(out + (((size_t)b0 * 512 + xo1) << 9) + (xg << 2));
        float4* o1 = (float4*)(out + (((size_t)(b0 + 1) * 512 + xo1) << 9) + (xg << 2));
        *o0 = make_float4(f0.x * inva1, f1.x * inva1, f2.x * inva1, f3.x * inva1);
        *o1 = make_float4(f0.y * inva1, f1.y * inva1, f2.y * inva1, f3.y * inva1);
    }
}

// ---------- host launch ----------
extern "C" void kernel_launch(void* const* d_in, const int* in_sizes, int n_in,
                              void* d_out, int out_size, void* d_ws, size_t ws_size,
                              hipStream_t stream)
{
    const float* yr  = (const float*)d_in[0];
    const float* yi  = (const float*)d_in[1];
    const float* uv  = (const float*)d_in[2];
    const float* wts = (const float*)d_in[3];

    int M = in_sizes[3];

    // ws layout (non-overlapping):
    //  [0,32)MB : gH (8 fp16 planar grids, 4 MB each)
    //  [32,40)MB: T (fp16, 8 MB)
    //  [64,96)MB: prep/grid scratch (cnt/list/yF4/pnt)
    __half2* gH = (__half2*)d_ws;
    __half2* T  = (__half2*)((char*)d_ws + ((size_t)32 << 20));
    char*    p2 = (char*)d_ws + ((size_t)64 << 20);
    int*    cnt  = (int*)p2;                                     // 64 KB
    int*    list = (int*)(p2 + 65536);                           // 6.29 MB
    float4* yF4  = (float4*)(p2 + 6553600);                      // 12.8 MB (M+1 pts)
    float4* pnt  = (float4*)(p2 + 19500032);                     // 12.8 MB (M+1 pts)

    hipMemsetAsync(cnt, 0, NBIN * sizeof(int), stream);
    int nb = (M + 255) / 256;
    prep_kernel<<<dim3(2 * nb), dim3(256), 0, stream>>>(
        yr, yi, uv, wts, yF4, pnt, cnt, list, M);
    grid_tile<<<dim3(NBIN / 4), dim3(256), 0, stream>>>(
        (const float*)pnt, (const float4*)yF4, cnt, list, gH, M);
    fft_pass1<<<dim3(4 * 128), dim3(256), 0, stream>>>(gH, T);
    fft_pass2<<<dim3(4 * 128), dim3(256), 0, stream>>>(T, (float*)d_out);
}